// Round 1
// baseline (804.528 us; speedup 1.0000x reference)
//
#include <hip/hip_runtime.h>
#include <hip/hip_bf16.h>
#include <stdint.h>

typedef __attribute__((ext_vector_type(8))) short bf16x8;
typedef __attribute__((ext_vector_type(4))) float f32x4;

__device__ __forceinline__ void load_lds16(const void* g, void* l){
  __builtin_amdgcn_global_load_lds((const __attribute__((address_space(1))) void*)g,
                                   (__attribute__((address_space(3))) void*)l, 16, 0, 0);
}

__device__ __forceinline__ float bf2f(unsigned int u){
  union { unsigned int i; float f; } x; x.i = u << 16; return x.f;
}
__device__ __forceinline__ unsigned short f2bf(float f){
  __hip_bfloat16 h = __float2bfloat16(f);
  unsigned short u;
  __builtin_memcpy(&u, &h, 2);
  return u;
}

// ---------- conversions ----------
__global__ void cvt_x_kernel(const float4* __restrict__ in, ushort4* __restrict__ out, int n4){
  int i = blockIdx.x*256 + threadIdx.x;
  if (i < n4){
    float4 v = in[i];
    ushort4 o;
    o.x = f2bf(v.x); o.y = f2bf(v.y); o.z = f2bf(v.z); o.w = f2bf(v.w);
    out[i] = o;
  }
}

// Wt[n][k] = bf16(W[k][n]) for n < N, 0 for N <= n < Npad
__global__ void wtrans_kernel(const float* __restrict__ W, unsigned short* __restrict__ Wt,
                              int K, int N, int Npad){
  int idx = blockIdx.x*256 + threadIdx.x;
  if (idx >= Npad*K) return;
  int nn = idx / K, kk = idx - nn*K;
  float v = (nn < N) ? W[(size_t)kk*N + nn] : 0.f;
  Wt[idx] = f2bf(v);
}

// ---------- graph preprocessing ----------
__global__ void hist_kernel(const int* __restrict__ col, int E, int* __restrict__ deg){
  int i = blockIdx.x*256 + threadIdx.x;
  if (i < E) atomicAdd(&deg[col[i]], 1);
}

__global__ void dis_kernel(const int* __restrict__ d1, const int* __restrict__ d2,
                           float* __restrict__ s1, float* __restrict__ s2, int n){
  int i = blockIdx.x*256 + threadIdx.x;
  if (i < n){
    int a = d1[i]; s1[i] = (a > 0) ? (1.0f/sqrtf((float)a)) : 0.f;
    int b = d2[i]; s2[i] = (b > 0) ? (1.0f/sqrtf((float)b)) : 0.f;
  }
}

__global__ void scan1_kernel(const int* __restrict__ deg1, const int* __restrict__ deg2,
                             int* __restrict__ off1, int* __restrict__ off2,
                             int* __restrict__ bsum, int n){
  __shared__ int s[1024];
  int set = blockIdx.y;
  const int* deg = set ? deg2 : deg1;
  int* off = set ? off2 : off1;
  int tid = threadIdx.x;
  int i = blockIdx.x*1024 + tid;
  int v = (i < n) ? deg[i] : 0;
  s[tid] = v;
  __syncthreads();
  for (int o = 1; o < 1024; o <<= 1){
    int t = (tid >= o) ? s[tid - o] : 0;
    __syncthreads();
    s[tid] += t;
    __syncthreads();
  }
  if (i < n) off[i] = s[tid];          // inclusive, chunk-local (fixed in pass 3)
  if (tid == 1023) bsum[set*64 + blockIdx.x] = s[1023];
}

__global__ void scan2_kernel(const int* __restrict__ bsum, int* __restrict__ bbase,
                             int nch, int* __restrict__ off1, int* __restrict__ off2, int n){
  int set = threadIdx.x;
  if (set < 2){
    int run = 0;
    for (int j = 0; j < nch; ++j){ bbase[set*64 + j] = run; run += bsum[set*64 + j]; }
    (set ? off2 : off1)[n] = run;      // total edge count
  }
}

__global__ void scan3_kernel(const int* __restrict__ deg1, const int* __restrict__ deg2,
                             int* __restrict__ off1, int* __restrict__ off2,
                             const int* __restrict__ bbase, int n){
  int set = blockIdx.y;
  const int* deg = set ? deg2 : deg1;
  int* off = set ? off2 : off1;
  int i = blockIdx.x*1024 + threadIdx.x;
  if (i < n){
    int e = off[i] + bbase[set*64 + blockIdx.x];
    off[i] = e - deg[i];               // exclusive global prefix
  }
}

// pack {row, dis[row]} per edge, bucketed by destination col
__global__ void scatter_kernel(const int* __restrict__ ei, int E,
                               const int* __restrict__ off, int* __restrict__ cur,
                               const float* __restrict__ dis, int2* __restrict__ csr){
  int e = blockIdx.x*256 + threadIdx.x;
  if (e >= E) return;
  int r = ei[e], c = ei[E + e];
  int p = off[c] + atomicAdd(&cur[c], 1);
  int2 rec; rec.x = r; rec.y = __float_as_int(dis[r]);
  csr[p] = rec;
}

// ---------- GCN aggregation: out[c] = dis[c] * sum_e dis[r]*hw[r] + b ----------
// one wave per node, lane handles 2 of 128 features (bf16x2 = 4B coalesced gather)
__global__ void conv_kernel(const int* __restrict__ off, const int2* __restrict__ csr,
                            const float* __restrict__ dis, const unsigned int* __restrict__ hw32,
                            const float* __restrict__ bias, unsigned short* __restrict__ outR,
                            int n, int col_ofs){
  int wv = blockIdx.x*4 + (threadIdx.x >> 6);
  int l = threadIdx.x & 63;
  if (wv >= n) return;
  int s = off[wv], e = off[wv + 1];
  float a0 = 0.f, a1 = 0.f;
  for (int p = s; p < e; ++p){
    int2 rec = csr[p];                                  // broadcast 8B load
    float dr = __int_as_float(rec.y);
    unsigned int hv = hw32[(size_t)rec.x*64 + l];       // 256B coalesced row gather
    a0 = fmaf(dr, bf2f(hv & 0xffffu), a0);
    a1 = fmaf(dr, bf2f(hv >> 16), a1);
  }
  float dc = dis[wv];
  float o0 = fmaf(dc, a0, bias[l*2 + 0]);
  float o1 = fmaf(dc, a1, bias[l*2 + 1]);
  unsigned int ov = (unsigned int)f2bf(o0) | ((unsigned int)f2bf(o1) << 16);
  *(unsigned int*)&outR[(size_t)wv*256 + col_ofs + l*2] = ov;
}

// ---------- bf16 MFMA GEMM, m97-style 2-barrier loop ----------
// A [M x K] bf16 row-major (lda), Bt = B^T stored [BN_total x K] bf16.
// EPI 0: plain bf16 store; EPI 1: +bias, relu, bf16 store;
// EPI 2: A = 3 slabs (h|R1|R2, lda=256 each), +bias, fused log_softmax, f32 store.
template<int FM, int FN, int WGM, int WGN, int EPI>
__global__ __launch_bounds__(256, 2) void gemm_kernel(
    const unsigned short* __restrict__ A0, const unsigned short* __restrict__ A1,
    const unsigned short* __restrict__ A2,
    const unsigned short* __restrict__ Bt, const float* __restrict__ bias,
    void* __restrict__ Cout, int M, int K, int lda, int ldc)
{
  constexpr int BM = WGM*FM*16;
  constexpr int BN = WGN*FN*16;
  constexpr int BK = 32;
  static_assert(BM == 128, "staging assumes BM==128");
  __shared__ unsigned short As[BM][BK];
  __shared__ unsigned short Bs[BN][BK];
  const int tid = threadIdx.x;
  const int w = tid >> 6, l = tid & 63;
  const int wr = w / WGN, wc = w % WGN;
  const int m0 = blockIdx.x*BM, n0 = blockIdx.y*BN;
  f32x4 acc[FM][FN] = {};
  const int nsteps = K / BK;
  for (int s = 0; s < nsteps; ++s){
    const int k0 = s*BK;
    const unsigned short* Asrc = A0;
    int kin = k0;
    if constexpr (EPI == 2){
      int slab = k0 >> 8;
      Asrc = (slab == 0) ? A0 : ((slab == 1) ? A1 : A2);
      kin = k0 & 255;
    }
    __syncthreads();
    #pragma unroll
    for (int j = 0; j < 2; ++j){           // A: 8KB = 2 x 4KB issues
      int idx = j*256 + tid;
      int row = idx >> 2, kq = idx & 3;
      int rg = m0 + row; rg = (rg < M) ? rg : (M - 1);
      load_lds16(Asrc + (size_t)rg*lda + kin + kq*8,
                 ((char*)&As[0][0]) + (size_t)(j*256 + w*64)*16);
    }
    #pragma unroll
    for (int j = 0; j < BN/64; ++j){       // Bt: [n][k] layout, same pattern as A
      int idx = j*256 + tid;
      int row = idx >> 2, kq = idx & 3;
      load_lds16(Bt + (size_t)(n0 + row)*K + k0 + kq*8,
                 ((char*)&Bs[0][0]) + (size_t)(j*256 + w*64)*16);
    }
    __syncthreads();
    bf16x8 af[FM], bfr[FN];
    const int kofs = (l >> 4)*8, l16 = l & 15;
    #pragma unroll
    for (int mi = 0; mi < FM; ++mi)
      af[mi] = *(const bf16x8*)&As[wr*FM*16 + mi*16 + l16][kofs];
    #pragma unroll
    for (int ni = 0; ni < FN; ++ni)
      bfr[ni] = *(const bf16x8*)&Bs[wc*FN*16 + ni*16 + l16][kofs];
    #pragma unroll
    for (int mi = 0; mi < FM; ++mi)
      #pragma unroll
      for (int ni = 0; ni < FN; ++ni)
        acc[mi][ni] = __builtin_amdgcn_mfma_f32_16x16x32_bf16(af[mi], bfr[ni], acc[mi][ni], 0, 0, 0);
  }
  const int lg = l >> 4, lc = l & 15;
  if constexpr (EPI == 2){
    float* O = (float*)Cout;
    #pragma unroll
    for (int mi = 0; mi < FM; ++mi){
      #pragma unroll
      for (int i = 0; i < 4; ++i){
        int row = m0 + wr*FM*16 + mi*16 + lg*4 + i;
        float v[FN];
        float mx = -1e30f;
        #pragma unroll
        for (int ni = 0; ni < FN; ++ni){
          int col = ni*16 + lc;                       // WGN==1, n0==0
          v[ni] = acc[mi][ni][i] + ((col < 40) ? bias[col] : 0.f);
          if (col < 40) mx = fmaxf(mx, v[ni]);
        }
        #pragma unroll
        for (int d = 1; d < 16; d <<= 1) mx = fmaxf(mx, __shfl_xor(mx, d, 64));
        float se = 0.f;
        #pragma unroll
        for (int ni = 0; ni < FN; ++ni){
          int col = ni*16 + lc;
          if (col < 40) se += expf(v[ni] - mx);
        }
        #pragma unroll
        for (int d = 1; d < 16; d <<= 1) se += __shfl_xor(se, d, 64);
        float lse = logf(se);
        if (row < M){
          #pragma unroll
          for (int ni = 0; ni < FN; ++ni){
            int col = ni*16 + lc;
            if (col < 40) O[(size_t)row*40 + col] = v[ni] - mx - lse;
          }
        }
      }
    }
  } else {
    unsigned short* C = (unsigned short*)Cout;
    #pragma unroll
    for (int mi = 0; mi < FM; ++mi){
      #pragma unroll
      for (int i = 0; i < 4; ++i){
        int row = m0 + wr*FM*16 + mi*16 + lg*4 + i;
        if (row >= M) continue;
        #pragma unroll
        for (int ni = 0; ni < FN; ++ni){
          int col = n0 + wc*FN*16 + ni*16 + lc;
          float vv = acc[mi][ni][i];
          if constexpr (EPI == 1){ vv += bias[col]; vv = fmaxf(vv, 0.f); }
          C[(size_t)row*ldc + col] = f2bf(vv);
        }
      }
    }
  }
}

extern "C" void kernel_launch(void* const* d_in, const int* in_sizes, int n_in,
                              void* d_out, int out_size, void* d_ws, size_t ws_size,
                              hipStream_t stream)
{
  (void)n_in; (void)out_size;
  const float* x      = (const float*)d_in[0];
  const int*   ei1    = (const int*)d_in[1];
  const int*   ei2    = (const int*)d_in[2];
  const float* W_lin1 = (const float*)d_in[3];
  const float* b_lin1 = (const float*)d_in[4];
  const float* W_c1   = (const float*)d_in[5];
  const float* b_c1   = (const float*)d_in[6];
  const float* W_c2   = (const float*)d_in[7];
  const float* b_c2   = (const float*)d_in[8];
  const float* W_lin2 = (const float*)d_in[9];
  const float* b_lin2 = (const float*)d_in[10];

  const int N  = in_sizes[0] / 512;
  const int E1 = in_sizes[1] / 2;
  const int E2 = in_sizes[2] / 2;

  char* base = (char*)d_ws;
  size_t off = 0;
  auto alloc = [&](size_t bytes) -> char* {
    off = (off + 255) & ~(size_t)255;
    char* r = base + off;
    off += bytes;
    return r;
  };
  unsigned short* xb   = (unsigned short*)alloc((size_t)N*512*2);
  unsigned short* h    = (unsigned short*)alloc((size_t)N*256*2);
  unsigned short* hw   = (unsigned short*)alloc((size_t)N*128*2);  // hw1 then reused as hw2
  unsigned short* R1   = (unsigned short*)alloc((size_t)N*256*2);
  unsigned short* R2   = (unsigned short*)alloc((size_t)N*256*2);
  unsigned short* Wt1  = (unsigned short*)alloc((size_t)256*512*2);
  unsigned short* Wtc1 = (unsigned short*)alloc((size_t)128*256*2);
  unsigned short* Wtc2 = (unsigned short*)alloc((size_t)128*256*2);
  unsigned short* Wtf  = (unsigned short*)alloc((size_t)64*768*2); // W_lin2^T padded to 64 cols
  int* degblk = (int*)alloc((size_t)4*N*4);
  int* deg1 = degblk, *deg2 = degblk + N, *cur1 = degblk + 2*N, *cur2 = degblk + 3*N;
  float* dis1 = (float*)alloc((size_t)N*4);
  float* dis2 = (float*)alloc((size_t)N*4);
  int* off1 = (int*)alloc((size_t)(N+1)*4);
  int* off2 = (int*)alloc((size_t)(N+1)*4);
  int* bsum  = (int*)alloc(128*4);
  int* bbase = (int*)alloc(128*4);
  int2* csr1 = (int2*)alloc((size_t)E1*8);
  int2* csr2 = (int2*)alloc((size_t)E2*8);
  if (off > ws_size) return;   // workspace insufficient -> visible validation failure

  hipMemsetAsync(degblk, 0, (size_t)4*N*4, stream);

  cvt_x_kernel<<<(N*512/4 + 255)/256, 256, 0, stream>>>((const float4*)x, (ushort4*)xb, N*512/4);
  wtrans_kernel<<<(256*512 + 255)/256, 256, 0, stream>>>(W_lin1, Wt1, 512, 256, 256);
  wtrans_kernel<<<(128*256 + 255)/256, 256, 0, stream>>>(W_c1, Wtc1, 256, 128, 128);
  wtrans_kernel<<<(128*256 + 255)/256, 256, 0, stream>>>(W_c2, Wtc2, 256, 128, 128);
  wtrans_kernel<<<(64*768 + 255)/256, 256, 0, stream>>>(W_lin2, Wtf, 768, 40, 64);

  hist_kernel<<<(E1 + 255)/256, 256, 0, stream>>>(ei1 + E1, E1, deg1);
  hist_kernel<<<(E2 + 255)/256, 256, 0, stream>>>(ei2 + E2, E2, deg2);
  dis_kernel<<<(N + 255)/256, 256, 0, stream>>>(deg1, deg2, dis1, dis2, N);

  int nch = (N + 1023)/1024;
  scan1_kernel<<<dim3(nch, 2), 1024, 0, stream>>>(deg1, deg2, off1, off2, bsum, N);
  scan2_kernel<<<1, 64, 0, stream>>>(bsum, bbase, nch, off1, off2, N);
  scan3_kernel<<<dim3(nch, 2), 1024, 0, stream>>>(deg1, deg2, off1, off2, bbase, N);

  scatter_kernel<<<(E1 + 255)/256, 256, 0, stream>>>(ei1, E1, off1, cur1, dis1, csr1);
  scatter_kernel<<<(E2 + 255)/256, 256, 0, stream>>>(ei2, E2, off2, cur2, dis2, csr2);

  int mt = (N + 127)/128;
  int cb = (N + 3)/4;
  // h = relu(x @ W_lin1 + b)
  gemm_kernel<4,4,2,2,1><<<dim3(mt, 2), 256, 0, stream>>>(xb, nullptr, nullptr, Wt1, b_lin1, h, N, 512, 512, 256);
  // hw1 = h @ W_c1 (shared by both layer-1 convs)
  gemm_kernel<4,4,2,2,0><<<dim3(mt, 1), 256, 0, stream>>>(h, nullptr, nullptr, Wtc1, nullptr, hw, N, 256, 256, 128);
  conv_kernel<<<cb, 256, 0, stream>>>(off1, csr1, dis1, (const unsigned int*)hw, b_c1, R1, N, 0);
  conv_kernel<<<cb, 256, 0, stream>>>(off2, csr2, dis2, (const unsigned int*)hw, b_c1, R1, N, 128);
  // hw2 = R1 @ W_c2 (shared by both layer-2 convs)
  gemm_kernel<4,4,2,2,0><<<dim3(mt, 1), 256, 0, stream>>>(R1, nullptr, nullptr, Wtc2, nullptr, hw, N, 256, 256, 128);
  conv_kernel<<<cb, 256, 0, stream>>>(off1, csr1, dis1, (const unsigned int*)hw, b_c2, R2, N, 0);
  conv_kernel<<<cb, 256, 0, stream>>>(off2, csr2, dis2, (const unsigned int*)hw, b_c2, R2, N, 128);
  // logits = [h|R1|R2] @ W_lin2 + b, fused log_softmax
  gemm_kernel<2,4,4,1,2><<<dim3(mt, 1), 256, 0, stream>>>(h, R1, R2, Wtf, b_lin2, d_out, N, 768, 256, 40);
}

// Round 2
// 583.971 us; speedup vs baseline: 1.3777x; 1.3777x over previous
//
#include <hip/hip_runtime.h>
#include <hip/hip_bf16.h>
#include <stdint.h>

typedef __attribute__((ext_vector_type(8))) short bf16x8;
typedef __attribute__((ext_vector_type(4))) float f32x4;

__device__ __forceinline__ void load_lds16(const void* g, void* l){
  __builtin_amdgcn_global_load_lds((const __attribute__((address_space(1))) void*)g,
                                   (__attribute__((address_space(3))) void*)l, 16, 0, 0);
}

__device__ __forceinline__ float bf2f(unsigned int u){
  union { unsigned int i; float f; } x; x.i = u << 16; return x.f;
}
__device__ __forceinline__ unsigned short f2bf(float f){
  __hip_bfloat16 h = __float2bfloat16(f);
  unsigned short u;
  __builtin_memcpy(&u, &h, 2);
  return u;
}

// ---------- conversions ----------
__global__ void cvt_x_kernel(const float4* __restrict__ in, ushort4* __restrict__ out, int n4){
  int i = blockIdx.x*256 + threadIdx.x;
  if (i < n4){
    float4 v = in[i];
    ushort4 o;
    o.x = f2bf(v.x); o.y = f2bf(v.y); o.z = f2bf(v.z); o.w = f2bf(v.w);
    out[i] = o;
  }
}

// Wt[n][k] = bf16(W[k][n]) for n < N, 0 for N <= n < Npad
__global__ void wtrans_kernel(const float* __restrict__ W, unsigned short* __restrict__ Wt,
                              int K, int N, int Npad){
  int idx = blockIdx.x*256 + threadIdx.x;
  if (idx >= Npad*K) return;
  int nn = idx / K, kk = idx - nn*K;
  float v = (nn < N) ? W[(size_t)kk*N + nn] : 0.f;
  Wt[idx] = f2bf(v);
}

// ---------- graph preprocessing ----------
__global__ void hist_kernel(const int* __restrict__ col, int E, int* __restrict__ deg){
  int i = blockIdx.x*256 + threadIdx.x;
  if (i < E) atomicAdd(&deg[col[i]], 1);
}

__global__ void dis_kernel(const int* __restrict__ d1, const int* __restrict__ d2,
                           float* __restrict__ s1, float* __restrict__ s2, int n){
  int i = blockIdx.x*256 + threadIdx.x;
  if (i < n){
    int a = d1[i]; s1[i] = (a > 0) ? (1.0f/sqrtf((float)a)) : 0.f;
    int b = d2[i]; s2[i] = (b > 0) ? (1.0f/sqrtf((float)b)) : 0.f;
  }
}

__global__ void scan1_kernel(const int* __restrict__ deg1, const int* __restrict__ deg2,
                             int* __restrict__ off1, int* __restrict__ off2,
                             int* __restrict__ bsum, int n){
  __shared__ int s[1024];
  int set = blockIdx.y;
  const int* deg = set ? deg2 : deg1;
  int* off = set ? off2 : off1;
  int tid = threadIdx.x;
  int i = blockIdx.x*1024 + tid;
  int v = (i < n) ? deg[i] : 0;
  s[tid] = v;
  __syncthreads();
  for (int o = 1; o < 1024; o <<= 1){
    int t = (tid >= o) ? s[tid - o] : 0;
    __syncthreads();
    s[tid] += t;
    __syncthreads();
  }
  if (i < n) off[i] = s[tid];          // inclusive, chunk-local (fixed in pass 3)
  if (tid == 1023) bsum[set*64 + blockIdx.x] = s[1023];
}

__global__ void scan2_kernel(const int* __restrict__ bsum, int* __restrict__ bbase,
                             int nch, int* __restrict__ off1, int* __restrict__ off2, int n){
  int set = threadIdx.x;
  if (set < 2){
    int run = 0;
    for (int j = 0; j < nch; ++j){ bbase[set*64 + j] = run; run += bsum[set*64 + j]; }
    (set ? off2 : off1)[n] = run;      // total edge count
  }
}

__global__ void scan3_kernel(const int* __restrict__ deg1, const int* __restrict__ deg2,
                             int* __restrict__ off1, int* __restrict__ off2,
                             const int* __restrict__ bbase, int n){
  int set = blockIdx.y;
  const int* deg = set ? deg2 : deg1;
  int* off = set ? off2 : off1;
  int i = blockIdx.x*1024 + threadIdx.x;
  if (i < n){
    int e = off[i] + bbase[set*64 + blockIdx.x];
    off[i] = e - deg[i];               // exclusive global prefix
  }
}

// pack {row, dis[row]} per edge, bucketed by destination col
__global__ void scatter_kernel(const int* __restrict__ ei, int E,
                               const int* __restrict__ off, int* __restrict__ cur,
                               const float* __restrict__ dis, int2* __restrict__ csr){
  int e = blockIdx.x*256 + threadIdx.x;
  if (e >= E) return;
  int r = ei[e], c = ei[E + e];
  int p = off[c] + atomicAdd(&cur[c], 1);
  int2 rec; rec.x = r; rec.y = __float_as_int(dis[r]);
  csr[p] = rec;
}

// ---------- GCN aggregation: out[c] = dis[c] * sum_e dis[r]*hw[r] + b ----------
// Fused over both edge sets (blockIdx.y). One wave per node, lane = 2 features.
// Edge loop unrolled x8: 8 CSR recs -> 8 independent row gathers in flight (MLP).
// CSR stream + output use nontemporal to keep hw gather table resident in L2.
__global__ void conv_kernel(const int* __restrict__ off1, const int2* __restrict__ csr1,
                            const float* __restrict__ dis1,
                            const int* __restrict__ off2, const int2* __restrict__ csr2,
                            const float* __restrict__ dis2,
                            const unsigned int* __restrict__ hw32,
                            const float* __restrict__ bias, unsigned short* __restrict__ outR,
                            int n){
  const int set = blockIdx.y;
  const int* __restrict__ off = set ? off2 : off1;
  const float* __restrict__ dis = set ? dis2 : dis1;
  const unsigned long long* __restrict__ csrq =
      (const unsigned long long*)(set ? csr2 : csr1);
  const int col_ofs = set ? 128 : 0;

  int wv = blockIdx.x*4 + (threadIdx.x >> 6);
  int l = threadIdx.x & 63;
  if (wv >= n) return;
  int s = off[wv], e = off[wv + 1];
  float a0 = 0.f, a1 = 0.f;
  int p = s;
  for (; p + 8 <= e; p += 8){
    unsigned long long q0 = __builtin_nontemporal_load(csrq + p + 0);
    unsigned long long q1 = __builtin_nontemporal_load(csrq + p + 1);
    unsigned long long q2 = __builtin_nontemporal_load(csrq + p + 2);
    unsigned long long q3 = __builtin_nontemporal_load(csrq + p + 3);
    unsigned long long q4 = __builtin_nontemporal_load(csrq + p + 4);
    unsigned long long q5 = __builtin_nontemporal_load(csrq + p + 5);
    unsigned long long q6 = __builtin_nontemporal_load(csrq + p + 6);
    unsigned long long q7 = __builtin_nontemporal_load(csrq + p + 7);
    unsigned int v0 = hw32[(size_t)(unsigned)(q0 & 0xffffffffu)*64 + l];
    unsigned int v1 = hw32[(size_t)(unsigned)(q1 & 0xffffffffu)*64 + l];
    unsigned int v2 = hw32[(size_t)(unsigned)(q2 & 0xffffffffu)*64 + l];
    unsigned int v3 = hw32[(size_t)(unsigned)(q3 & 0xffffffffu)*64 + l];
    unsigned int v4 = hw32[(size_t)(unsigned)(q4 & 0xffffffffu)*64 + l];
    unsigned int v5 = hw32[(size_t)(unsigned)(q5 & 0xffffffffu)*64 + l];
    unsigned int v6 = hw32[(size_t)(unsigned)(q6 & 0xffffffffu)*64 + l];
    unsigned int v7 = hw32[(size_t)(unsigned)(q7 & 0xffffffffu)*64 + l];
    float d0 = __int_as_float((unsigned)(q0 >> 32));
    float d1 = __int_as_float((unsigned)(q1 >> 32));
    float d2 = __int_as_float((unsigned)(q2 >> 32));
    float d3 = __int_as_float((unsigned)(q3 >> 32));
    float d4 = __int_as_float((unsigned)(q4 >> 32));
    float d5 = __int_as_float((unsigned)(q5 >> 32));
    float d6 = __int_as_float((unsigned)(q6 >> 32));
    float d7 = __int_as_float((unsigned)(q7 >> 32));
    a0 = fmaf(d0, bf2f(v0 & 0xffffu), a0); a1 = fmaf(d0, bf2f(v0 >> 16), a1);
    a0 = fmaf(d1, bf2f(v1 & 0xffffu), a0); a1 = fmaf(d1, bf2f(v1 >> 16), a1);
    a0 = fmaf(d2, bf2f(v2 & 0xffffu), a0); a1 = fmaf(d2, bf2f(v2 >> 16), a1);
    a0 = fmaf(d3, bf2f(v3 & 0xffffu), a0); a1 = fmaf(d3, bf2f(v3 >> 16), a1);
    a0 = fmaf(d4, bf2f(v4 & 0xffffu), a0); a1 = fmaf(d4, bf2f(v4 >> 16), a1);
    a0 = fmaf(d5, bf2f(v5 & 0xffffu), a0); a1 = fmaf(d5, bf2f(v5 >> 16), a1);
    a0 = fmaf(d6, bf2f(v6 & 0xffffu), a0); a1 = fmaf(d6, bf2f(v6 >> 16), a1);
    a0 = fmaf(d7, bf2f(v7 & 0xffffu), a0); a1 = fmaf(d7, bf2f(v7 >> 16), a1);
  }
  for (; p < e; ++p){
    unsigned long long q = __builtin_nontemporal_load(csrq + p);
    unsigned int hv = hw32[(size_t)(unsigned)(q & 0xffffffffu)*64 + l];
    float dr = __int_as_float((unsigned)(q >> 32));
    a0 = fmaf(dr, bf2f(hv & 0xffffu), a0);
    a1 = fmaf(dr, bf2f(hv >> 16), a1);
  }
  float dc = dis[wv];
  float o0 = fmaf(dc, a0, bias[l*2 + 0]);
  float o1 = fmaf(dc, a1, bias[l*2 + 1]);
  unsigned int ov = (unsigned int)f2bf(o0) | ((unsigned int)f2bf(o1) << 16);
  __builtin_nontemporal_store(ov, (unsigned int*)&outR[(size_t)wv*256 + col_ofs + l*2]);
}

// ---------- bf16 MFMA GEMM, m97-style 2-barrier loop ----------
// A [M x K] bf16 row-major (lda), Bt = B^T stored [BN_total x K] bf16.
// EPI 0: plain bf16 store; EPI 1: +bias, relu, bf16 store;
// EPI 2: A = 3 slabs (h|R1|R2, lda=256 each), +bias, fused log_softmax, f32 store.
template<int FM, int FN, int WGM, int WGN, int EPI>
__global__ __launch_bounds__(256, 2) void gemm_kernel(
    const unsigned short* __restrict__ A0, const unsigned short* __restrict__ A1,
    const unsigned short* __restrict__ A2,
    const unsigned short* __restrict__ Bt, const float* __restrict__ bias,
    void* __restrict__ Cout, int M, int K, int lda, int ldc)
{
  constexpr int BM = WGM*FM*16;
  constexpr int BN = WGN*FN*16;
  constexpr int BK = 32;
  static_assert(BM == 128, "staging assumes BM==128");
  __shared__ unsigned short As[BM][BK];
  __shared__ unsigned short Bs[BN][BK];
  const int tid = threadIdx.x;
  const int w = tid >> 6, l = tid & 63;
  const int wr = w / WGN, wc = w % WGN;
  const int m0 = blockIdx.x*BM, n0 = blockIdx.y*BN;
  f32x4 acc[FM][FN] = {};
  const int nsteps = K / BK;
  for (int s = 0; s < nsteps; ++s){
    const int k0 = s*BK;
    const unsigned short* Asrc = A0;
    int kin = k0;
    if constexpr (EPI == 2){
      int slab = k0 >> 8;
      Asrc = (slab == 0) ? A0 : ((slab == 1) ? A1 : A2);
      kin = k0 & 255;
    }
    __syncthreads();
    #pragma unroll
    for (int j = 0; j < 2; ++j){           // A: 8KB = 2 x 4KB issues
      int idx = j*256 + tid;
      int row = idx >> 2, kq = idx & 3;
      int rg = m0 + row; rg = (rg < M) ? rg : (M - 1);
      load_lds16(Asrc + (size_t)rg*lda + kin + kq*8,
                 ((char*)&As[0][0]) + (size_t)(j*256 + w*64)*16);
    }
    #pragma unroll
    for (int j = 0; j < BN/64; ++j){       // Bt: [n][k] layout, same pattern as A
      int idx = j*256 + tid;
      int row = idx >> 2, kq = idx & 3;
      load_lds16(Bt + (size_t)(n0 + row)*K + k0 + kq*8,
                 ((char*)&Bs[0][0]) + (size_t)(j*256 + w*64)*16);
    }
    __syncthreads();
    bf16x8 af[FM], bfr[FN];
    const int kofs = (l >> 4)*8, l16 = l & 15;
    #pragma unroll
    for (int mi = 0; mi < FM; ++mi)
      af[mi] = *(const bf16x8*)&As[wr*FM*16 + mi*16 + l16][kofs];
    #pragma unroll
    for (int ni = 0; ni < FN; ++ni)
      bfr[ni] = *(const bf16x8*)&Bs[wc*FN*16 + ni*16 + l16][kofs];
    #pragma unroll
    for (int mi = 0; mi < FM; ++mi)
      #pragma unroll
      for (int ni = 0; ni < FN; ++ni)
        acc[mi][ni] = __builtin_amdgcn_mfma_f32_16x16x32_bf16(af[mi], bfr[ni], acc[mi][ni], 0, 0, 0);
  }
  const int lg = l >> 4, lc = l & 15;
  if constexpr (EPI == 2){
    float* O = (float*)Cout;
    #pragma unroll
    for (int mi = 0; mi < FM; ++mi){
      #pragma unroll
      for (int i = 0; i < 4; ++i){
        int row = m0 + wr*FM*16 + mi*16 + lg*4 + i;
        float v[FN];
        float mx = -1e30f;
        #pragma unroll
        for (int ni = 0; ni < FN; ++ni){
          int col = ni*16 + lc;                       // WGN==1, n0==0
          v[ni] = acc[mi][ni][i] + ((col < 40) ? bias[col] : 0.f);
          if (col < 40) mx = fmaxf(mx, v[ni]);
        }
        #pragma unroll
        for (int d = 1; d < 16; d <<= 1) mx = fmaxf(mx, __shfl_xor(mx, d, 64));
        float se = 0.f;
        #pragma unroll
        for (int ni = 0; ni < FN; ++ni){
          int col = ni*16 + lc;
          if (col < 40) se += expf(v[ni] - mx);
        }
        #pragma unroll
        for (int d = 1; d < 16; d <<= 1) se += __shfl_xor(se, d, 64);
        float lse = logf(se);
        if (row < M){
          #pragma unroll
          for (int ni = 0; ni < FN; ++ni){
            int col = ni*16 + lc;
            if (col < 40) O[(size_t)row*40 + col] = v[ni] - mx - lse;
          }
        }
      }
    }
  } else {
    unsigned short* C = (unsigned short*)Cout;
    #pragma unroll
    for (int mi = 0; mi < FM; ++mi){
      #pragma unroll
      for (int i = 0; i < 4; ++i){
        int row = m0 + wr*FM*16 + mi*16 + lg*4 + i;
        if (row >= M) continue;
        #pragma unroll
        for (int ni = 0; ni < FN; ++ni){
          int col = n0 + wc*FN*16 + ni*16 + lc;
          float vv = acc[mi][ni][i];
          if constexpr (EPI == 1){ vv += bias[col]; vv = fmaxf(vv, 0.f); }
          C[(size_t)row*ldc + col] = f2bf(vv);
        }
      }
    }
  }
}

extern "C" void kernel_launch(void* const* d_in, const int* in_sizes, int n_in,
                              void* d_out, int out_size, void* d_ws, size_t ws_size,
                              hipStream_t stream)
{
  (void)n_in; (void)out_size;
  const float* x      = (const float*)d_in[0];
  const int*   ei1    = (const int*)d_in[1];
  const int*   ei2    = (const int*)d_in[2];
  const float* W_lin1 = (const float*)d_in[3];
  const float* b_lin1 = (const float*)d_in[4];
  const float* W_c1   = (const float*)d_in[5];
  const float* b_c1   = (const float*)d_in[6];
  const float* W_c2   = (const float*)d_in[7];
  const float* b_c2   = (const float*)d_in[8];
  const float* W_lin2 = (const float*)d_in[9];
  const float* b_lin2 = (const float*)d_in[10];

  const int N  = in_sizes[0] / 512;
  const int E1 = in_sizes[1] / 2;
  const int E2 = in_sizes[2] / 2;

  char* base = (char*)d_ws;
  size_t off = 0;
  auto alloc = [&](size_t bytes) -> char* {
    off = (off + 255) & ~(size_t)255;
    char* r = base + off;
    off += bytes;
    return r;
  };
  unsigned short* xb   = (unsigned short*)alloc((size_t)N*512*2);
  unsigned short* h    = (unsigned short*)alloc((size_t)N*256*2);
  unsigned short* hw   = (unsigned short*)alloc((size_t)N*128*2);  // hw1 then reused as hw2
  unsigned short* R1   = (unsigned short*)alloc((size_t)N*256*2);
  unsigned short* R2   = (unsigned short*)alloc((size_t)N*256*2);
  unsigned short* Wt1  = (unsigned short*)alloc((size_t)256*512*2);
  unsigned short* Wtc1 = (unsigned short*)alloc((size_t)128*256*2);
  unsigned short* Wtc2 = (unsigned short*)alloc((size_t)128*256*2);
  unsigned short* Wtf  = (unsigned short*)alloc((size_t)64*768*2); // W_lin2^T padded to 64 cols
  int* degblk = (int*)alloc((size_t)4*N*4);
  int* deg1 = degblk, *deg2 = degblk + N, *cur1 = degblk + 2*N, *cur2 = degblk + 3*N;
  float* dis1 = (float*)alloc((size_t)N*4);
  float* dis2 = (float*)alloc((size_t)N*4);
  int* off1 = (int*)alloc((size_t)(N+1)*4);
  int* off2 = (int*)alloc((size_t)(N+1)*4);
  int* bsum  = (int*)alloc(128*4);
  int* bbase = (int*)alloc(128*4);
  int2* csr1 = (int2*)alloc((size_t)E1*8);
  int2* csr2 = (int2*)alloc((size_t)E2*8);
  if (off > ws_size) return;   // workspace insufficient -> visible validation failure

  hipMemsetAsync(degblk, 0, (size_t)4*N*4, stream);

  cvt_x_kernel<<<(N*512/4 + 255)/256, 256, 0, stream>>>((const float4*)x, (ushort4*)xb, N*512/4);
  wtrans_kernel<<<(256*512 + 255)/256, 256, 0, stream>>>(W_lin1, Wt1, 512, 256, 256);
  wtrans_kernel<<<(128*256 + 255)/256, 256, 0, stream>>>(W_c1, Wtc1, 256, 128, 128);
  wtrans_kernel<<<(128*256 + 255)/256, 256, 0, stream>>>(W_c2, Wtc2, 256, 128, 128);
  wtrans_kernel<<<(64*768 + 255)/256, 256, 0, stream>>>(W_lin2, Wtf, 768, 40, 64);

  hist_kernel<<<(E1 + 255)/256, 256, 0, stream>>>(ei1 + E1, E1, deg1);
  hist_kernel<<<(E2 + 255)/256, 256, 0, stream>>>(ei2 + E2, E2, deg2);
  dis_kernel<<<(N + 255)/256, 256, 0, stream>>>(deg1, deg2, dis1, dis2, N);

  int nch = (N + 1023)/1024;
  scan1_kernel<<<dim3(nch, 2), 1024, 0, stream>>>(deg1, deg2, off1, off2, bsum, N);
  scan2_kernel<<<1, 64, 0, stream>>>(bsum, bbase, nch, off1, off2, N);
  scan3_kernel<<<dim3(nch, 2), 1024, 0, stream>>>(deg1, deg2, off1, off2, bbase, N);

  scatter_kernel<<<(E1 + 255)/256, 256, 0, stream>>>(ei1, E1, off1, cur1, dis1, csr1);
  scatter_kernel<<<(E2 + 255)/256, 256, 0, stream>>>(ei2, E2, off2, cur2, dis2, csr2);

  int mt = (N + 127)/128;
  int cb = (N + 3)/4;
  // h = relu(x @ W_lin1 + b)
  gemm_kernel<4,4,2,2,1><<<dim3(mt, 2), 256, 0, stream>>>(xb, nullptr, nullptr, Wt1, b_lin1, h, N, 512, 512, 256);
  // hw1 = h @ W_c1 (shared by both layer-1 convs)
  gemm_kernel<4,4,2,2,0><<<dim3(mt, 1), 256, 0, stream>>>(h, nullptr, nullptr, Wtc1, nullptr, hw, N, 256, 256, 128);
  // layer-1 convs fused over both edge sets
  conv_kernel<<<dim3(cb, 2), 256, 0, stream>>>(off1, csr1, dis1, off2, csr2, dis2,
                                               (const unsigned int*)hw, b_c1, R1, N);
  // hw2 = R1 @ W_c2 (shared by both layer-2 convs)
  gemm_kernel<4,4,2,2,0><<<dim3(mt, 1), 256, 0, stream>>>(R1, nullptr, nullptr, Wtc2, nullptr, hw, N, 256, 256, 128);
  conv_kernel<<<dim3(cb, 2), 256, 0, stream>>>(off1, csr1, dis1, off2, csr2, dis2,
                                               (const unsigned int*)hw, b_c2, R2, N);
  // logits = [h|R1|R2] @ W_lin2 + b, fused log_softmax
  gemm_kernel<2,4,4,1,2><<<dim3(mt, 1), 256, 0, stream>>>(h, R1, R2, Wtf, b_lin2, d_out, N, 768, 256, 40);
}